// Round 9
// baseline (515.581 us; speedup 1.0000x reference)
//
#include <hip/hip_runtime.h>
#include <math.h>
#include <cstddef>

// Problem constants
#define BB   16
#define HH   256
#define WW   256
#define CC   64      // channels (= attention token count)
#define NTOK 16      // pooled tokens per (b,c)
#define NDIM 16      // DIM

// ws layout:
//   part : [B][16 tok][16 rc][64 c] fp32  = 262144 floats (1 MiB)
//   frag : [B][8 slot][64 lane][8 j] bf16 =  65536 ushorts (128 KiB)
//     per-batch: 8*64*8 = 4096 ushorts = 512 fragments of 16 B.
//     slot = tt*2 + kstep
//     element: W[t = tt*16 + (lane&15)][c = kstep*32 + (lane>>4)*8 + j]
//     Same lane mapping serves as A-frag (row=t) or B-frag (col=t) of
//     mfma_f32_16x16x32_bf16 — v10 uses it as the A operand.
//   SINGLE bf16: attn ~= 1/64 uniform (dots ~ +-2.4e-4), out in +-0.8;
//   single-RNE-bf16 error max ~1e-3 << 8.7e-3 budget (verified r6-r8).
#define PART_FLOATS (BB * NTOK * 16 * CC)
#define FRAG_USHORT_PER_B (8 * 64 * 8)   // 4096

typedef short s16x8 __attribute__((ext_vector_type(8)));   // 8 bf16 (4 VGPRs)
typedef float f32x4 __attribute__((ext_vector_type(4)));

// bf16 RNE helper (scalar, used in stage 2 only)
__device__ __forceinline__ unsigned short f2bf_rne(float f) {
    unsigned int u = __float_as_uint(f);
    return (unsigned short)((u + 0x7fffu + ((u >> 16) & 1u)) >> 16);
}

// ---------------------------------------------------------------------------
// Stage 1: partial pooling sums. (unchanged — near coalesced floor)
// ---------------------------------------------------------------------------
__global__ __launch_bounds__(256) void pool_partial(const float* __restrict__ x,
                                                    float* __restrict__ part) {
    const int blk = blockIdx.x;       // b*256 + n*16 + rc
    const int rc  = blk & 15;
    const int n   = (blk >> 4) & 15;
    const int b   = blk >> 8;
    const int ph  = n >> 2, pw = n & 3;
    const int t   = threadIdx.x;
    const int c4  = (t & 15) << 2;
    const int sub = t >> 4;           // 0..15

    const int h0 = ph * 64 + rc * 4;
    const int w0 = pw * 64;
    const float* xb = x + (((size_t)b * HH + h0) * WW + w0) * CC;

    float4 s = make_float4(0.f, 0.f, 0.f, 0.f);
#pragma unroll
    for (int k = 0; k < 16; ++k) {
        const int pos = sub + (k << 4);       // 0..255
        const int row = pos >> 6;
        const int col = pos & 63;
        const float4 v = *(const float4*)(xb + ((size_t)row * WW + col) * CC + c4);
        s.x += v.x; s.y += v.y; s.z += v.z; s.w += v.w;
    }

    __shared__ float lds[16 * 64];
    lds[sub * 64 + c4 + 0] = s.x;
    lds[sub * 64 + c4 + 1] = s.y;
    lds[sub * 64 + c4 + 2] = s.z;
    lds[sub * 64 + c4 + 3] = s.w;
    __syncthreads();

    if (t < 64) {
        float acc = 0.f;
#pragma unroll
        for (int ss = 0; ss < 16; ++ss) acc += lds[ss * 64 + t];
        part[(((size_t)b * NTOK + n) * 16 + rc) * CC + t] = acc;
    }
}

// ---------------------------------------------------------------------------
// Stage 2: tokens -> qk -> dots -> softmax -> bf16 B-fragments (RNE).
// grid = 16 (one per batch). Phase-1 uses float4 loads (r8).
// ---------------------------------------------------------------------------
__global__ __launch_bounds__(256) void attn_kernel(const float* __restrict__ part,
                                                   const float* __restrict__ w_qkv, // [32][16]
                                                   unsigned short* __restrict__ fragw) {
    const int b = blockIdx.x;
    const int t = threadIdx.x;

    __shared__ float tok[CC * NDIM];   // [c][n]
    __shared__ float ql [CC * NDIM];   // [c][n]
    __shared__ float kl [CC * NDIM];   // [c][n]
    __shared__ float dl [CC * CC];     // [i][j]
    __shared__ float rs [CC];          // 1/rowsum

    const float* pb = part + (size_t)b * NTOK * 16 * CC;

    // tokens[c][n] = mean over patch = (sum of 16 rc-partials)/4096
    {
        const int n  = t >> 4;
        const int cq = t & 15;
        float4 a = make_float4(0.f, 0.f, 0.f, 0.f);
#pragma unroll
        for (int rc = 0; rc < 16; ++rc) {
            const float4 v = *(const float4*)(pb + ((size_t)n * 16 + rc) * CC + cq * 4);
            a.x += v.x; a.y += v.y; a.z += v.z; a.w += v.w;
        }
        tok[(cq * 4 + 0) * NDIM + n] = a.x * (1.0f / 4096.0f);
        tok[(cq * 4 + 1) * NDIM + n] = a.y * (1.0f / 4096.0f);
        tok[(cq * 4 + 2) * NDIM + n] = a.z * (1.0f / 4096.0f);
        tok[(cq * 4 + 3) * NDIM + n] = a.w * (1.0f / 4096.0f);
    }
    __syncthreads();

    // qk[c][d] = sum_n tok[c][n] * w[d][n];  split into q (d<16) and k
    for (int idx = t; idx < CC * 32; idx += 256) {
        const int c = idx >> 5, d = idx & 31;
        float a = 0.f;
#pragma unroll
        for (int n = 0; n < NDIM; ++n) a += tok[c * NDIM + n] * w_qkv[d * NDIM + n];
        if (d < 16) ql[c * NDIM + d] = a;
        else        kl[c * NDIM + (d - 16)] = a;
    }
    __syncthreads();

    // dots[i][j] = 0.25 * sum_n q[i][n]*k[j][n]
    for (int idx = t; idx < CC * CC; idx += 256) {
        const int i = idx >> 6, j = idx & 63;
        float a = 0.f;
#pragma unroll
        for (int n = 0; n < NDIM; ++n) a += ql[i * NDIM + n] * kl[j * NDIM + n];
        dl[idx] = a * 0.25f;
    }
    __syncthreads();

    // row softmax (64 rows, one thread each — tiny)
    if (t < CC) {
        float m = -1e30f;
        for (int j = 0; j < CC; ++j) m = fmaxf(m, dl[t * CC + j]);
        float ssum = 0.f;
        for (int j = 0; j < CC; ++j) {
            const float e = expf(dl[t * CC + j] - m);
            dl[t * CC + j] = e;
            ssum += e;
        }
        rs[t] = 1.0f / ssum;
    }
    __syncthreads();

    // Emit attn[t][c] = dl[t][c]*rs[t] as bf16 MFMA fragments.
    for (int idx = t; idx < 512; idx += 256) {
        const int tt   = idx >> 3;          // 0..63
        const int oct  = idx & 7;           // c octet
        const int ks   = oct >> 2;          // kstep = c>>5
        const int g    = oct & 3;           // lane>>4 group
        const int slot = (tt >> 4) * 2 + ks;         // 0..7
        const int lanei = (tt & 15) + g * 16;
        const float rr = rs[tt];
        s16x8 hi;
#pragma unroll
        for (int j = 0; j < 8; ++j)
            hi[j] = (short)f2bf_rne(dl[tt * CC + oct * 8 + j] * rr);
        s16x8* dst = (s16x8*)fragw + ((size_t)b * 8 + slot) * 64;
        dst[lanei] = hi;
    }
}

// ---------------------------------------------------------------------------
// Stage 3 (v10): operand-SWAPPED single-bf16 MFMA GEMM, float4 stores.
// out[p][t] = gelu(sum_c x[p][c]*attn[t][c])
// v10 vs v9: compute D = attn x x^T instead of x x attn^T —
//   mfma(attn_frag, x_frag, acc). A/B fragments share the same lane mapping
//   (row/col = l&15, k = (l>>4)*8+j), so the existing x loads and frag
//   buffer work unchanged as the opposite operands. D now has row=t,
//   col=pixel: each thread's 4 acc regs are 4 CONSECUTIVE t of one pixel
//   -> one dwordx4 store per (pt,tt): 16 float4 stores/thread vs 64 scalar.
//   Each wave store = 1 KB in 16x64B contiguous chunks (was 256 B in 4
//   half-lines). Stores are the only never-ablated structural element
//   (r5 traversal, r6 issue count, r7 LDS/barrier/depth, r8 L3 residency:
//   all null); round-0's float4-store kernel is the evidence they matter.
// ---------------------------------------------------------------------------
__device__ __forceinline__ float gelu_fast(float v) {
    // gelu ~= v * sigmoid(1.59576912v + 0.07135482v^3); |err|<2e-4 for |v|<~1.
    const float u = v * v;
    const float z = v * fmaf(0.07135482f, u, 1.59576912f);
    const float e = exp2f(z * -1.44269504f);            // e^{-z}
    return v * __builtin_amdgcn_rcpf(e + 1.0f);
}

// pack 8 fp32 -> 8 bf16 (RNE) via v_cvt_pk_bf16_f32 (1 instr per 2 elems)
__device__ __forceinline__ s16x8 pack8(const float4 a, const float4 b) {
    union { unsigned int u[4]; s16x8 v; } r;
    asm("v_cvt_pk_bf16_f32 %0, %1, %2" : "=v"(r.u[0]) : "v"(a.x), "v"(a.y));
    asm("v_cvt_pk_bf16_f32 %0, %1, %2" : "=v"(r.u[1]) : "v"(a.z), "v"(a.w));
    asm("v_cvt_pk_bf16_f32 %0, %1, %2" : "=v"(r.u[2]) : "v"(b.x), "v"(b.y));
    asm("v_cvt_pk_bf16_f32 %0, %1, %2" : "=v"(r.u[3]) : "v"(b.z), "v"(b.w));
    return r.v;
}

__global__ __launch_bounds__(256) void out_mfma(const float* __restrict__ x,
                                                const unsigned short* __restrict__ frag,
                                                float* __restrict__ out) {
    const int tid  = threadIdx.x;
    const int lane = tid & 63;
    const int wv   = tid >> 6;
    const int blk  = blockIdx.x;          // 4096 blocks, 256 pixels each
    const int b    = blk >> 8;            // 256 blocks per batch
    const int row  = lane & 15;           // pixel-in-tile (x rows / D cols)
    const int g    = lane >> 4;

    const size_t pix0 = (size_t)blk * 256 + wv * 64;
    const float* xb = x + (pix0 + row) * CC + g * 8;

    // ---- issue x pixel-tile 0 ----
    float4 a0 = *(const float4*)(xb);
    float4 a1 = *(const float4*)(xb + 4);
    float4 a2 = *(const float4*)(xb + 32);
    float4 a3 = *(const float4*)(xb + 36);

    // ---- issue the 8 per-lane attn fragments (L2-hot, 16 B each) ----
    const s16x8* fb = (const s16x8*)(frag + (size_t)b * FRAG_USHORT_PER_B);
    s16x8 bf[8];
#pragma unroll
    for (int s = 0; s < 8; ++s) bf[s] = fb[s * 64 + lane];

    // ---- issue x pixel-tile 1 ----
    const float* x1 = xb + 16 * CC;
    float4 b0v = *(const float4*)(x1);
    float4 b1v = *(const float4*)(x1 + 4);
    float4 b2v = *(const float4*)(x1 + 32);
    float4 b3v = *(const float4*)(x1 + 36);

    // store base: pixel = lane&15 (D col), t-quad base = g*4 (D rows)
    float* ob = out + (pix0 + row) * CC + (g << 2);

#define TCOLS(PT, XH0, XH1)                                                      \
    _Pragma("unroll")                                                            \
    for (int tt = 0; tt < 4; ++tt) {                                             \
        f32x4 acc = {0.f, 0.f, 0.f, 0.f};                                        \
        acc = __builtin_amdgcn_mfma_f32_16x16x32_bf16(bf[tt * 2], XH0, acc, 0, 0, 0);     \
        acc = __builtin_amdgcn_mfma_f32_16x16x32_bf16(bf[tt * 2 + 1], XH1, acc, 0, 0, 0); \
        f32x4 gv;                                                                \
        gv.x = gelu_fast(acc.x); gv.y = gelu_fast(acc.y);                        \
        gv.z = gelu_fast(acc.z); gv.w = gelu_fast(acc.w);                        \
        *(f32x4*)(ob + (size_t)(PT) * 16 * CC + tt * 16) = gv;                   \
    }

    // pt0: compute from A-buf, prefetch pt2 into A-buf
    {
        const s16x8 xh0 = pack8(a0, a1);
        const s16x8 xh1 = pack8(a2, a3);
        const float* nx = xb + 32 * CC;
        a0 = *(const float4*)(nx);
        a1 = *(const float4*)(nx + 4);
        a2 = *(const float4*)(nx + 32);
        a3 = *(const float4*)(nx + 36);
        TCOLS(0, xh0, xh1)
    }
    // pt1: compute from B-buf, prefetch pt3 into B-buf
    {
        const s16x8 xh0 = pack8(b0v, b1v);
        const s16x8 xh1 = pack8(b2v, b3v);
        const float* nx = xb + 48 * CC;
        b0v = *(const float4*)(nx);
        b1v = *(const float4*)(nx + 4);
        b2v = *(const float4*)(nx + 32);
        b3v = *(const float4*)(nx + 36);
        TCOLS(1, xh0, xh1)
    }
    // pt2: compute from A-buf
    {
        const s16x8 xh0 = pack8(a0, a1);
        const s16x8 xh1 = pack8(a2, a3);
        TCOLS(2, xh0, xh1)
    }
    // pt3: compute from B-buf
    {
        const s16x8 xh0 = pack8(b0v, b1v);
        const s16x8 xh1 = pack8(b2v, b3v);
        TCOLS(3, xh0, xh1)
    }
#undef TCOLS
}

// ---------------------------------------------------------------------------
extern "C" void kernel_launch(void* const* d_in, const int* in_sizes, int n_in,
                              void* d_out, int out_size, void* d_ws, size_t ws_size,
                              hipStream_t stream) {
    const float* x     = (const float*)d_in[0];   // (16,256,256,64) fp32
    const float* w_qkv = (const float*)d_in[1];   // (32,16) fp32
    float* out   = (float*)d_out;                 // (16,256,256,64) fp32
    float* part  = (float*)d_ws;                  // 1 MiB
    unsigned short* frag = (unsigned short*)(part + PART_FLOATS); // 128 KiB

    pool_partial<<<BB * NTOK * 16, 256, 0, stream>>>(x, part);
    attn_kernel<<<BB, 256, 0, stream>>>(part, w_qkv, frag);
    out_mfma<<<BB * 256, 256, 0, stream>>>(x, frag, out);
}